// Round 1
// baseline (384.638 us; speedup 1.0000x reference)
//
#include <hip/hip_runtime.h>
#include <hip/hip_bf16.h>
#include <cmath>

#define T_DIM 512
#define N_DIM 512
#define M_DIM 256
#define B_DIM 256

#define BM 128
#define BN 128
#define BK 32
#define LDK 40   // padded LDS row stride (elements); 80 B = 16-byte multiple

typedef __bf16 bf16x8 __attribute__((ext_vector_type(8)));
typedef float  f32x4  __attribute__((ext_vector_type(4)));

__device__ __forceinline__ void bsplit(float x, __bf16 &hi, __bf16 &lo) {
    __bf16 h = (__bf16)x;
    hi = h;
    lo = (__bf16)(x - (float)h);
}

// wq[b,t] = sum_k concat(h_t[b],s_t[b])[k] * W_e[t,k]
__global__ __launch_bounds__(256) void wq_kernel(
    const float* __restrict__ h_t, const float* __restrict__ s_t,
    const float* __restrict__ W_e, float* __restrict__ wq)
{
    __shared__ float q[2 * M_DIM];
    const int b = blockIdx.x;
    const int tid = threadIdx.x;
    q[tid]         = h_t[(size_t)b * M_DIM + tid];
    q[M_DIM + tid] = s_t[(size_t)b * M_DIM + tid];
    __syncthreads();
    for (int tt = tid; tt < T_DIM; tt += 256) {
        const float4* wrow = (const float4*)(W_e + (size_t)tt * (2 * M_DIM));
        float acc = 0.f;
        #pragma unroll 4
        for (int k4 = 0; k4 < (2 * M_DIM) / 4; ++k4) {
            float4 w = wrow[k4];
            acc += q[4*k4+0] * w.x + q[4*k4+1] * w.y
                 + q[4*k4+2] * w.z + q[4*k4+3] * w.w;
        }
        wq[(size_t)b * T_DIM + tt] = acc;
    }
}

// Per workgroup: C[n,s] = sum_t data[b,t,n0+n] * U_e[s0+s,t]  (128x128, K=512)
// via split-bf16 MFMA (hi*hi + lo*hi + hi*lo), then
// partial[b,sb,n] = sum_{s in block} v_e[s] * tanh(wq[b,s] + C[n,s])
__global__ __launch_bounds__(256) void fused_kernel(
    const float* __restrict__ data, const float* __restrict__ U_e,
    const float* __restrict__ v_e, const float* __restrict__ wq,
    float* __restrict__ partial)
{
    __shared__ __align__(16) __bf16 Ah[BM][LDK];
    __shared__ __align__(16) __bf16 Al[BM][LDK];
    __shared__ __align__(16) __bf16 Bh[BN][LDK];
    __shared__ __align__(16) __bf16 Bl[BN][LDK];
    __shared__ float sc[BM];

    const int wg = blockIdx.x;
    const int b  = wg >> 4;          // 256 batches
    const int nb = (wg >> 2) & 3;    // n-block
    const int sb = wg & 3;           // s-block

    const int tid  = threadIdx.x;
    const int lane = tid & 63;
    const int wid  = tid >> 6;       // 4 waves, 2x2
    const int wm   = wid >> 1;
    const int wn   = wid & 1;

    if (tid < BM) sc[tid] = 0.f;

    f32x4 acc[4][4];
    const f32x4 zero = {0.f, 0.f, 0.f, 0.f};
    #pragma unroll
    for (int i = 0; i < 4; ++i)
        #pragma unroll
        for (int j = 0; j < 4; ++j)
            acc[i][j] = zero;

    const float* dataB = data + (size_t)b * T_DIM * N_DIM + nb * BM;
    const int fr = lane & 15;
    const int kb = (lane >> 4) * 8;

    for (int k0 = 0; k0 < T_DIM; k0 += BK) {
        __syncthreads();
        // ---- stage A: A[n][k] = data[b, k0+k, nb*128+n], transpose on write
        {
            const int k  = tid >> 3;   // 0..31
            const int nq = tid & 7;    // 0..7
            const float* src = dataB + (size_t)(k0 + k) * N_DIM;
            #pragma unroll
            for (int r = 0; r < 4; ++r) {
                const int n = (nq + r * 8) * 4;
                float4 v = *(const float4*)(src + n);
                __bf16 h, l;
                bsplit(v.x, h, l); Ah[n+0][k] = h; Al[n+0][k] = l;
                bsplit(v.y, h, l); Ah[n+1][k] = h; Al[n+1][k] = l;
                bsplit(v.z, h, l); Ah[n+2][k] = h; Al[n+2][k] = l;
                bsplit(v.w, h, l); Ah[n+3][k] = h; Al[n+3][k] = l;
            }
        }
        // ---- stage B: B[s][k] = U_e[sb*128+s, k0+k]  (already k-contiguous)
        {
            const int s  = tid >> 1;     // 0..127
            const int kq = tid & 1;
            const float* src = U_e + (size_t)(sb * BN + s) * T_DIM + k0;
            #pragma unroll
            for (int r = 0; r < 4; ++r) {
                const int k = (kq * 4 + r) * 4;
                float4 v = *(const float4*)(src + k);
                __bf16 h0,l0,h1,l1,h2,l2,h3,l3;
                bsplit(v.x, h0, l0); bsplit(v.y, h1, l1);
                bsplit(v.z, h2, l2); bsplit(v.w, h3, l3);
                Bh[s][k+0] = h0; Bh[s][k+1] = h1; Bh[s][k+2] = h2; Bh[s][k+3] = h3;
                Bl[s][k+0] = l0; Bl[s][k+1] = l1; Bl[s][k+2] = l2; Bl[s][k+3] = l3;
            }
        }
        __syncthreads();

        // ---- fragments + MFMA (3 split terms)
        bf16x8 ah[4], al[4], bh[4], bl[4];
        #pragma unroll
        for (int mi = 0; mi < 4; ++mi) {
            const int row = wm * 64 + mi * 16 + fr;
            ah[mi] = *(const bf16x8*)&Ah[row][kb];
            al[mi] = *(const bf16x8*)&Al[row][kb];
        }
        #pragma unroll
        for (int ni = 0; ni < 4; ++ni) {
            const int col = wn * 64 + ni * 16 + fr;
            bh[ni] = *(const bf16x8*)&Bh[col][kb];
            bl[ni] = *(const bf16x8*)&Bl[col][kb];
        }
        #pragma unroll
        for (int mi = 0; mi < 4; ++mi)
            #pragma unroll
            for (int ni = 0; ni < 4; ++ni) {
                acc[mi][ni] = __builtin_amdgcn_mfma_f32_16x16x32_bf16(ah[mi], bh[ni], acc[mi][ni], 0, 0, 0);
                acc[mi][ni] = __builtin_amdgcn_mfma_f32_16x16x32_bf16(al[mi], bh[ni], acc[mi][ni], 0, 0, 0);
                acc[mi][ni] = __builtin_amdgcn_mfma_f32_16x16x32_bf16(ah[mi], bl[ni], acc[mi][ni], 0, 0, 0);
            }
    }

    // ---- epilogue: tanh + v-weighted reduce over this block's 128 s-columns
    float wqv[4], vev[4];
    #pragma unroll
    for (int ni = 0; ni < 4; ++ni) {
        const int scol = sb * BN + wn * 64 + ni * 16 + fr;
        wqv[ni] = wq[(size_t)b * T_DIM + scol];
        vev[ni] = v_e[scol];
    }
    const int g = lane >> 4;
    #pragma unroll
    for (int mi = 0; mi < 4; ++mi) {
        #pragma unroll
        for (int rg = 0; rg < 4; ++rg) {
            float part = 0.f;
            #pragma unroll
            for (int ni = 0; ni < 4; ++ni)
                part += vev[ni] * tanhf(wqv[ni] + acc[mi][ni][rg]);
            // reduce over the 16 column-lanes (masks stay within 16-group)
            part += __shfl_xor(part, 1);
            part += __shfl_xor(part, 2);
            part += __shfl_xor(part, 4);
            part += __shfl_xor(part, 8);
            if (fr == 0)
                atomicAdd(&sc[wm * 64 + mi * 16 + 4 * g + rg], part);
            // sc[row] receives exactly 2 adds (wn=0,1): f32-commutative -> deterministic
        }
    }
    __syncthreads();
    if (tid < BM)
        partial[((size_t)b * 4 + sb) * N_DIM + nb * BM + tid] = sc[tid];
}

// scores[b,n] = sum_sb partial[b,sb,n]; out = softmax over n
__global__ __launch_bounds__(512) void softmax_kernel(
    const float* __restrict__ partial, float* __restrict__ out)
{
    const int b = blockIdx.x;
    const int n = threadIdx.x;
    const float* p = partial + (size_t)b * 4 * N_DIM;
    float s = p[n] + p[N_DIM + n] + p[2 * N_DIM + n] + p[3 * N_DIM + n];

    float m = s;
    #pragma unroll
    for (int off = 1; off < 64; off <<= 1)
        m = fmaxf(m, __shfl_xor(m, off));
    __shared__ float red[8];
    const int wv = n >> 6;
    if ((n & 63) == 0) red[wv] = m;
    __syncthreads();
    float bm = red[0];
    #pragma unroll
    for (int i = 1; i < 8; ++i) bm = fmaxf(bm, red[i]);

    float e = expf(s - bm);
    float t = e;
    #pragma unroll
    for (int off = 1; off < 64; off <<= 1)
        t += __shfl_xor(t, off);
    __syncthreads();
    if ((n & 63) == 0) red[wv] = t;
    __syncthreads();
    float tot = 0.f;
    #pragma unroll
    for (int i = 0; i < 8; ++i) tot += red[i];

    out[(size_t)b * N_DIM + n] = e / tot;
}

extern "C" void kernel_launch(void* const* d_in, const int* in_sizes, int n_in,
                              void* d_out, int out_size, void* d_ws, size_t ws_size,
                              hipStream_t stream) {
    const float* h_t  = (const float*)d_in[0];
    const float* s_t  = (const float*)d_in[1];
    const float* data = (const float*)d_in[2];
    const float* W_e  = (const float*)d_in[3];
    const float* U_e  = (const float*)d_in[4];
    const float* v_e  = (const float*)d_in[5];
    float* out = (float*)d_out;

    float* wq      = (float*)d_ws;                       // B*T floats
    float* partial = wq + (size_t)B_DIM * T_DIM;         // B*4*N floats

    wq_kernel<<<B_DIM, 256, 0, stream>>>(h_t, s_t, W_e, wq);
    fused_kernel<<<B_DIM * 16, 256, 0, stream>>>(data, U_e, v_e, wq, partial);
    softmax_kernel<<<B_DIM, 512, 0, stream>>>(partial, out);
}

// Round 2
// 313.409 us; speedup vs baseline: 1.2273x; 1.2273x over previous
//
#include <hip/hip_runtime.h>
#include <hip/hip_bf16.h>
#include <cmath>

#define T_DIM 512
#define N_DIM 512
#define M_DIM 256
#define B_DIM 256

typedef __bf16 bf16x8 __attribute__((ext_vector_type(8)));
typedef float  f32x4  __attribute__((ext_vector_type(4)));

__device__ __forceinline__ void bsplit(float x, __bf16 &hi, __bf16 &lo) {
    __bf16 h = (__bf16)x;
    hi = h;
    lo = (__bf16)(x - (float)h);
}

__device__ __forceinline__ void gload16(const __bf16* g, __bf16* l) {
    __builtin_amdgcn_global_load_lds(
        (const __attribute__((address_space(1))) void*)g,
        (__attribute__((address_space(3))) void*)l, 16, 0, 0);
}

// ---------------- precompute: U_e -> hi/lo bf16 ----------------
__global__ __launch_bounds__(256) void uconv_kernel(
    const float* __restrict__ U, __bf16* __restrict__ Uh, __bf16* __restrict__ Ul)
{
    const int i = (blockIdx.x * 256 + threadIdx.x) * 2;
    float2 v = *(const float2*)(U + i);
    __bf16 h, l;
    bsplit(v.x, h, l); Uh[i]   = h; Ul[i]   = l;
    bsplit(v.y, h, l); Uh[i+1] = h; Ul[i+1] = l;
}

// ---------------- precompute: data[b][t][n] -> dataT[b][n][t] bf16 (hi only) ----------------
__global__ __launch_bounds__(256) void transpose_kernel(
    const float* __restrict__ data, __bf16* __restrict__ dataT)
{
    __shared__ __align__(16) __bf16 tile[64][72];   // [n][t], rows 144 B (16B multiple)
    const int bid = blockIdx.x;
    const int b  = bid >> 6;
    const int tb = (bid >> 3) & 7;
    const int nb = bid & 7;
    const int tid = threadIdx.x;

    const float* src = data + ((size_t)b * T_DIM + tb * 64) * N_DIM + nb * 64;
    #pragma unroll
    for (int p = 0; p < 4; ++p) {
        const int r = p * 16 + (tid >> 4);      // t within tile
        const int c = (tid & 15) * 4;           // n within tile
        float4 v = *(const float4*)(src + (size_t)r * N_DIM + c);
        tile[c+0][r] = (__bf16)v.x;
        tile[c+1][r] = (__bf16)v.y;
        tile[c+2][r] = (__bf16)v.z;
        tile[c+3][r] = (__bf16)v.w;
    }
    __syncthreads();
    __bf16* dst = dataT + ((size_t)b * N_DIM + nb * 64) * T_DIM + tb * 64;
    #pragma unroll
    for (int p = 0; p < 2; ++p) {
        const int r = p * 32 + (tid >> 3);      // n within tile
        const int c = (tid & 7) * 8;            // t within tile
        *(bf16x8*)(dst + (size_t)r * T_DIM + c) = *(const bf16x8*)&tile[r][c];
    }
}

// ---------------- wq[b,t] = concat(h,s) . W_e[t,:] ----------------
__global__ __launch_bounds__(256) void wq_kernel(
    const float* __restrict__ h_t, const float* __restrict__ s_t,
    const float* __restrict__ W_e, float* __restrict__ wq)
{
    __shared__ float q[2 * M_DIM];
    const int b = blockIdx.x;
    const int tid = threadIdx.x;
    q[tid]         = h_t[(size_t)b * M_DIM + tid];
    q[M_DIM + tid] = s_t[(size_t)b * M_DIM + tid];
    __syncthreads();
    for (int tt = tid; tt < T_DIM; tt += 256) {
        const float4* wrow = (const float4*)(W_e + (size_t)tt * (2 * M_DIM));
        float acc = 0.f;
        #pragma unroll 4
        for (int k4 = 0; k4 < (2 * M_DIM) / 4; ++k4) {
            float4 w = wrow[k4];
            acc += q[4*k4+0] * w.x + q[4*k4+1] * w.y
                 + q[4*k4+2] * w.z + q[4*k4+3] * w.w;
        }
        wq[(size_t)b * T_DIM + tt] = acc;
    }
}

// ---------------- fused GEMM + tanh + v-dot (m97 structure, 2-term split) ----------------
__global__ __launch_bounds__(256) void fused2_kernel(
    const __bf16* __restrict__ dataT, const __bf16* __restrict__ Uh,
    const __bf16* __restrict__ Ul, const float* __restrict__ v_e,
    const float* __restrict__ wq, float* __restrict__ partial)
{
    __shared__ __align__(16) __bf16 As [128 * 32];
    __shared__ __align__(16) __bf16 Bhs[128 * 32];
    __shared__ __align__(16) __bf16 Bls[128 * 32];
    __shared__ float sc[128];

    const int wg = blockIdx.x;
    // XCD-aware decode: all 16 tiles of a batch share wg&7 -> same XCD -> dataT L2 reuse
    const int b    = (wg & 7) + ((wg >> 7) << 3);
    const int tile = (wg >> 3) & 15;
    const int nb   = tile >> 2;
    const int sb   = tile & 3;

    const int tid  = threadIdx.x;
    const int lane = tid & 63;
    const int wid  = tid >> 6;
    const int wm   = wid >> 1;
    const int wn   = wid & 1;

    if (tid < 128) sc[tid] = 0.f;

    f32x4 acc[4][4];
    const f32x4 zero = {0.f, 0.f, 0.f, 0.f};
    #pragma unroll
    for (int i = 0; i < 4; ++i)
        #pragma unroll
        for (int j = 0; j < 4; ++j)
            acc[i][j] = zero;

    const __bf16* Ab  = dataT + ((size_t)b * N_DIM + nb * 128) * T_DIM;
    const __bf16* Bhb = Uh + (size_t)(sb * 128) * T_DIM;
    const __bf16* Blb = Ul + (size_t)(sb * 128) * T_DIM;

    const int r0 = tid >> 2;            // row 0..63 (this thread's staging row)
    const int ce = (tid & 3) * 8;       // col element offset 0/8/16/24
    __bf16* lA = &As [tid * 8];         // linear dest == base + lane*16B
    __bf16* lBh = &Bhs[tid * 8];
    __bf16* lBl = &Bls[tid * 8];

    const int fr = lane & 15;
    const int kb = (lane >> 4) * 8;

    for (int k0 = 0; k0 < T_DIM; k0 += 32) {
        __syncthreads();   // previous tile fully consumed
        gload16(Ab  + (size_t)r0        * T_DIM + k0 + ce, lA);
        gload16(Ab  + (size_t)(r0 + 64) * T_DIM + k0 + ce, lA  + 64 * 32);
        gload16(Bhb + (size_t)r0        * T_DIM + k0 + ce, lBh);
        gload16(Bhb + (size_t)(r0 + 64) * T_DIM + k0 + ce, lBh + 64 * 32);
        gload16(Blb + (size_t)r0        * T_DIM + k0 + ce, lBl);
        gload16(Blb + (size_t)(r0 + 64) * T_DIM + k0 + ce, lBl + 64 * 32);
        __syncthreads();   // compiler drains vmcnt(0) before this barrier

        bf16x8 a[4], bh[4], bl[4];
        #pragma unroll
        for (int mi = 0; mi < 4; ++mi)
            a[mi] = *(const bf16x8*)&As[(wm * 64 + mi * 16 + fr) * 32 + kb];
        #pragma unroll
        for (int ni = 0; ni < 4; ++ni) {
            bh[ni] = *(const bf16x8*)&Bhs[(wn * 64 + ni * 16 + fr) * 32 + kb];
            bl[ni] = *(const bf16x8*)&Bls[(wn * 64 + ni * 16 + fr) * 32 + kb];
        }
        #pragma unroll
        for (int mi = 0; mi < 4; ++mi)
            #pragma unroll
            for (int ni = 0; ni < 4; ++ni) {
                acc[mi][ni] = __builtin_amdgcn_mfma_f32_16x16x32_bf16(a[mi], bh[ni], acc[mi][ni], 0, 0, 0);
                acc[mi][ni] = __builtin_amdgcn_mfma_f32_16x16x32_bf16(a[mi], bl[ni], acc[mi][ni], 0, 0, 0);
            }
    }

    // epilogue: tanh + v-weighted reduce over this block's 128 s-columns
    float wqv[4], vev[4];
    #pragma unroll
    for (int ni = 0; ni < 4; ++ni) {
        const int scol = sb * 128 + wn * 64 + ni * 16 + fr;
        wqv[ni] = wq[(size_t)b * T_DIM + scol];
        vev[ni] = v_e[scol];
    }
    const int g = lane >> 4;
    #pragma unroll
    for (int mi = 0; mi < 4; ++mi) {
        #pragma unroll
        for (int rg = 0; rg < 4; ++rg) {
            float part = 0.f;
            #pragma unroll
            for (int ni = 0; ni < 4; ++ni)
                part += vev[ni] * tanhf(wqv[ni] + acc[mi][ni][rg]);
            part += __shfl_xor(part, 1);
            part += __shfl_xor(part, 2);
            part += __shfl_xor(part, 4);
            part += __shfl_xor(part, 8);
            if (fr == 0)
                atomicAdd(&sc[wm * 64 + mi * 16 + 4 * g + rg], part);
            // exactly 2 adds per slot (wn=0,1): f32 add commutative -> deterministic
        }
    }
    __syncthreads();
    if (tid < 128)
        partial[((size_t)b * 4 + sb) * N_DIM + nb * 128 + tid] = sc[tid];
}

// ---------------- fallback (round-1 verified): inline-split fused kernel ----------------
__global__ __launch_bounds__(256) void fused_fallback_kernel(
    const float* __restrict__ data, const float* __restrict__ U_e,
    const float* __restrict__ v_e, const float* __restrict__ wq,
    float* __restrict__ partial)
{
#define BMf 128
#define LDKf 40
    __shared__ __align__(16) __bf16 Ah[BMf][LDKf];
    __shared__ __align__(16) __bf16 Al[BMf][LDKf];
    __shared__ __align__(16) __bf16 Bh[BMf][LDKf];
    __shared__ __align__(16) __bf16 Bl[BMf][LDKf];
    __shared__ float sc[BMf];

    const int wg = blockIdx.x;
    const int b  = wg >> 4;
    const int nb = (wg >> 2) & 3;
    const int sb = wg & 3;

    const int tid  = threadIdx.x;
    const int lane = tid & 63;
    const int wid  = tid >> 6;
    const int wm   = wid >> 1;
    const int wn   = wid & 1;

    if (tid < BMf) sc[tid] = 0.f;

    f32x4 acc[4][4];
    const f32x4 zero = {0.f, 0.f, 0.f, 0.f};
    #pragma unroll
    for (int i = 0; i < 4; ++i)
        #pragma unroll
        for (int j = 0; j < 4; ++j)
            acc[i][j] = zero;

    const float* dataB = data + (size_t)b * T_DIM * N_DIM + nb * BMf;
    const int fr = lane & 15;
    const int kb = (lane >> 4) * 8;

    for (int k0 = 0; k0 < T_DIM; k0 += 32) {
        __syncthreads();
        {
            const int k  = tid >> 3;
            const int nq = tid & 7;
            const float* src = dataB + (size_t)(k0 + k) * N_DIM;
            #pragma unroll
            for (int r = 0; r < 4; ++r) {
                const int n = (nq + r * 8) * 4;
                float4 v = *(const float4*)(src + n);
                __bf16 h, l;
                bsplit(v.x, h, l); Ah[n+0][k] = h; Al[n+0][k] = l;
                bsplit(v.y, h, l); Ah[n+1][k] = h; Al[n+1][k] = l;
                bsplit(v.z, h, l); Ah[n+2][k] = h; Al[n+2][k] = l;
                bsplit(v.w, h, l); Ah[n+3][k] = h; Al[n+3][k] = l;
            }
        }
        {
            const int s  = tid >> 1;
            const int kq = tid & 1;
            const float* src = U_e + (size_t)(sb * BMf + s) * T_DIM + k0;
            #pragma unroll
            for (int r = 0; r < 4; ++r) {
                const int k = (kq * 4 + r) * 4;
                float4 v = *(const float4*)(src + k);
                __bf16 h0,l0,h1,l1,h2,l2,h3,l3;
                bsplit(v.x, h0, l0); bsplit(v.y, h1, l1);
                bsplit(v.z, h2, l2); bsplit(v.w, h3, l3);
                Bh[s][k+0] = h0; Bh[s][k+1] = h1; Bh[s][k+2] = h2; Bh[s][k+3] = h3;
                Bl[s][k+0] = l0; Bl[s][k+1] = l1; Bl[s][k+2] = l2; Bl[s][k+3] = l3;
            }
        }
        __syncthreads();

        bf16x8 ah[4], al[4], bh[4], bl[4];
        #pragma unroll
        for (int mi = 0; mi < 4; ++mi) {
            const int row = wm * 64 + mi * 16 + fr;
            ah[mi] = *(const bf16x8*)&Ah[row][kb];
            al[mi] = *(const bf16x8*)&Al[row][kb];
        }
        #pragma unroll
        for (int ni = 0; ni < 4; ++ni) {
            const int col = wn * 64 + ni * 16 + fr;
            bh[ni] = *(const bf16x8*)&Bh[col][kb];
            bl[ni] = *(const bf16x8*)&Bl[col][kb];
        }
        #pragma unroll
        for (int mi = 0; mi < 4; ++mi)
            #pragma unroll
            for (int ni = 0; ni < 4; ++ni) {
                acc[mi][ni] = __builtin_amdgcn_mfma_f32_16x16x32_bf16(ah[mi], bh[ni], acc[mi][ni], 0, 0, 0);
                acc[mi][ni] = __builtin_amdgcn_mfma_f32_16x16x32_bf16(al[mi], bh[ni], acc[mi][ni], 0, 0, 0);
                acc[mi][ni] = __builtin_amdgcn_mfma_f32_16x16x32_bf16(ah[mi], bl[ni], acc[mi][ni], 0, 0, 0);
            }
    }

    float wqv[4], vev[4];
    #pragma unroll
    for (int ni = 0; ni < 4; ++ni) {
        const int scol = sb * BMf + wn * 64 + ni * 16 + fr;
        wqv[ni] = wq[(size_t)b * T_DIM + scol];
        vev[ni] = v_e[scol];
    }
    const int g = lane >> 4;
    #pragma unroll
    for (int mi = 0; mi < 4; ++mi) {
        #pragma unroll
        for (int rg = 0; rg < 4; ++rg) {
            float part = 0.f;
            #pragma unroll
            for (int ni = 0; ni < 4; ++ni)
                part += vev[ni] * tanhf(wqv[ni] + acc[mi][ni][rg]);
            part += __shfl_xor(part, 1);
            part += __shfl_xor(part, 2);
            part += __shfl_xor(part, 4);
            part += __shfl_xor(part, 8);
            if (fr == 0)
                atomicAdd(&sc[wm * 64 + mi * 16 + 4 * g + rg], part);
        }
    }
    __syncthreads();
    if (tid < BMf)
        partial[((size_t)b * 4 + sb) * N_DIM + nb * BMf + tid] = sc[tid];
}

// ---------------- softmax ----------------
__global__ __launch_bounds__(512) void softmax_kernel(
    const float* __restrict__ partial, float* __restrict__ out)
{
    const int b = blockIdx.x;
    const int n = threadIdx.x;
    const float* p = partial + (size_t)b * 4 * N_DIM;
    float s = p[n] + p[N_DIM + n] + p[2 * N_DIM + n] + p[3 * N_DIM + n];

    float m = s;
    #pragma unroll
    for (int off = 1; off < 64; off <<= 1)
        m = fmaxf(m, __shfl_xor(m, off));
    __shared__ float red[8];
    const int wv = n >> 6;
    if ((n & 63) == 0) red[wv] = m;
    __syncthreads();
    float bm = red[0];
    #pragma unroll
    for (int i = 1; i < 8; ++i) bm = fmaxf(bm, red[i]);

    float e = expf(s - bm);
    float t = e;
    #pragma unroll
    for (int off = 1; off < 64; off <<= 1)
        t += __shfl_xor(t, off);
    __syncthreads();
    if ((n & 63) == 0) red[wv] = t;
    __syncthreads();
    float tot = 0.f;
    #pragma unroll
    for (int i = 0; i < 8; ++i) tot += red[i];

    out[(size_t)b * N_DIM + n] = e / tot;
}

extern "C" void kernel_launch(void* const* d_in, const int* in_sizes, int n_in,
                              void* d_out, int out_size, void* d_ws, size_t ws_size,
                              hipStream_t stream) {
    const float* h_t  = (const float*)d_in[0];
    const float* s_t  = (const float*)d_in[1];
    const float* data = (const float*)d_in[2];
    const float* W_e  = (const float*)d_in[3];
    const float* U_e  = (const float*)d_in[4];
    const float* v_e  = (const float*)d_in[5];
    float* out = (float*)d_out;

    const size_t wq_elems      = (size_t)B_DIM * T_DIM;            // f32
    const size_t partial_elems = (size_t)B_DIM * 4 * N_DIM;        // f32
    const size_t u_elems       = (size_t)T_DIM * T_DIM;            // bf16 each
    const size_t dT_elems      = (size_t)B_DIM * N_DIM * T_DIM;    // bf16

    float* wq      = (float*)d_ws;
    float* partial = wq + wq_elems;
    __bf16* Uh     = (__bf16*)(partial + partial_elems);
    __bf16* Ul     = Uh + u_elems;
    __bf16* dataT  = Ul + u_elems;

    const size_t need = (wq_elems + partial_elems) * 4 + (2 * u_elems + dT_elems) * 2;

    wq_kernel<<<B_DIM, 256, 0, stream>>>(h_t, s_t, W_e, wq);
    if (ws_size >= need) {
        uconv_kernel<<<(int)(u_elems / 512), 256, 0, stream>>>(U_e, Uh, Ul);
        transpose_kernel<<<B_DIM * 64, 256, 0, stream>>>(data, dataT);
        fused2_kernel<<<B_DIM * 16, 256, 0, stream>>>(dataT, Uh, Ul, v_e, wq, partial);
    } else {
        fused_fallback_kernel<<<B_DIM * 16, 256, 0, stream>>>(data, U_e, v_e, wq, partial);
    }
    softmax_kernel<<<B_DIM, 512, 0, stream>>>(partial, out);
}

// Round 3
// 242.320 us; speedup vs baseline: 1.5873x; 1.2934x over previous
//
#include <hip/hip_runtime.h>
#include <hip/hip_bf16.h>
#include <cmath>

#define T_DIM 512
#define N_DIM 512
#define M_DIM 256
#define B_DIM 256

typedef __bf16 bf16x8 __attribute__((ext_vector_type(8)));
typedef float  f32x4  __attribute__((ext_vector_type(4)));

__device__ __forceinline__ void bsplit(float x, __bf16 &hi, __bf16 &lo) {
    __bf16 h = (__bf16)x;
    hi = h;
    lo = (__bf16)(x - (float)h);
}

__device__ __forceinline__ void gload16(const __bf16* g, __bf16* l) {
    __builtin_amdgcn_global_load_lds(
        (const __attribute__((address_space(1))) void*)g,
        (__attribute__((address_space(3))) void*)l, 16, 0, 0);
}

// ---------------- precompute: U_e -> hi bf16 ----------------
__global__ __launch_bounds__(256) void uconv_kernel(
    const float* __restrict__ U, __bf16* __restrict__ Uh)
{
    const int i = (blockIdx.x * 256 + threadIdx.x) * 2;
    float2 v = *(const float2*)(U + i);
    Uh[i]   = (__bf16)v.x;
    Uh[i+1] = (__bf16)v.y;
}

// ---------------- precompute: data[b][t][n] -> dataT[b][n][t] bf16 ----------------
__global__ __launch_bounds__(256) void transpose_kernel(
    const float* __restrict__ data, __bf16* __restrict__ dataT)
{
    __shared__ __align__(16) __bf16 tile[64][72];   // [n][t]
    const int bid = blockIdx.x;
    const int b  = bid >> 6;
    const int tb = (bid >> 3) & 7;
    const int nb = bid & 7;
    const int tid = threadIdx.x;

    const float* src = data + ((size_t)b * T_DIM + tb * 64) * N_DIM + nb * 64;
    #pragma unroll
    for (int p = 0; p < 4; ++p) {
        const int r = p * 16 + (tid >> 4);      // t within tile
        const int c = (tid & 15) * 4;           // n within tile
        float4 v = *(const float4*)(src + (size_t)r * N_DIM + c);
        tile[c+0][r] = (__bf16)v.x;
        tile[c+1][r] = (__bf16)v.y;
        tile[c+2][r] = (__bf16)v.z;
        tile[c+3][r] = (__bf16)v.w;
    }
    __syncthreads();
    __bf16* dst = dataT + ((size_t)b * N_DIM + nb * 64) * T_DIM + tb * 64;
    #pragma unroll
    for (int p = 0; p < 2; ++p) {
        const int r = p * 32 + (tid >> 3);      // n within tile
        const int c = (tid & 7) * 8;            // t within tile
        *(bf16x8*)(dst + (size_t)r * T_DIM + c) = *(const bf16x8*)&tile[r][c];
    }
}

// ---------------- wq[b,t] = concat(h,s) . W_e[t,:] ----------------
__global__ __launch_bounds__(256) void wq_kernel(
    const float* __restrict__ h_t, const float* __restrict__ s_t,
    const float* __restrict__ W_e, float* __restrict__ wq)
{
    __shared__ float q[2 * M_DIM];
    const int b = blockIdx.x;
    const int tid = threadIdx.x;
    q[tid]         = h_t[(size_t)b * M_DIM + tid];
    q[M_DIM + tid] = s_t[(size_t)b * M_DIM + tid];
    __syncthreads();
    for (int tt = tid; tt < T_DIM; tt += 256) {
        const float4* wrow = (const float4*)(W_e + (size_t)tt * (2 * M_DIM));
        float acc = 0.f;
        #pragma unroll 4
        for (int k4 = 0; k4 < (2 * M_DIM) / 4; ++k4) {
            float4 w = wrow[k4];
            acc += q[4*k4+0] * w.x + q[4*k4+1] * w.y
                 + q[4*k4+2] * w.z + q[4*k4+3] * w.w;
        }
        wq[(size_t)b * T_DIM + tt] = acc;
    }
}

// ---------------- fused GEMM + tanh + v-dot (m97 structure, 1-term bf16) ----------------
__global__ __launch_bounds__(256) void fused1_kernel(
    const __bf16* __restrict__ dataT, const __bf16* __restrict__ Uh,
    const float* __restrict__ v_e, const float* __restrict__ wq,
    float* __restrict__ partial)
{
    __shared__ __align__(16) __bf16 As[128 * 32];
    __shared__ __align__(16) __bf16 Bs[128 * 32];
    __shared__ float sc[128];

    const int wg = blockIdx.x;
    // XCD-aware decode: all 16 tiles of a batch land on the same XCD -> A-panel L2 reuse
    const int b    = (wg & 7) + ((wg >> 7) << 3);
    const int tile = (wg >> 3) & 15;
    const int nb   = tile >> 2;
    const int sb   = tile & 3;

    const int tid  = threadIdx.x;
    const int lane = tid & 63;
    const int wid  = tid >> 6;
    const int wm   = wid >> 1;
    const int wn   = wid & 1;

    if (tid < 128) sc[tid] = 0.f;

    f32x4 acc[4][4];
    const f32x4 zero = {0.f, 0.f, 0.f, 0.f};
    #pragma unroll
    for (int i = 0; i < 4; ++i)
        #pragma unroll
        for (int j = 0; j < 4; ++j)
            acc[i][j] = zero;

    const __bf16* Ab = dataT + ((size_t)b * N_DIM + nb * 128) * T_DIM;
    const __bf16* Bb = Uh + (size_t)(sb * 128) * T_DIM;

    const int r0 = tid >> 2;            // staging row 0..63
    const int ce = (tid & 3) * 8;       // k-chunk (elements)
    __bf16* lA = &As[tid * 8];          // linear dest == wave base + lane*16B
    __bf16* lB = &Bs[tid * 8];

    const int fr = lane & 15;
    const int kb = (lane >> 4) * 8;

    for (int k0 = 0; k0 < T_DIM; k0 += 32) {
        __syncthreads();   // previous tile fully consumed
        gload16(Ab + (size_t)r0        * T_DIM + k0 + ce, lA);
        gload16(Ab + (size_t)(r0 + 64) * T_DIM + k0 + ce, lA + 64 * 32);
        gload16(Bb + (size_t)r0        * T_DIM + k0 + ce, lB);
        gload16(Bb + (size_t)(r0 + 64) * T_DIM + k0 + ce, lB + 64 * 32);
        __syncthreads();   // vmcnt(0) drained before barrier by compiler

        bf16x8 a[4], bv[4];
        #pragma unroll
        for (int mi = 0; mi < 4; ++mi)
            a[mi] = *(const bf16x8*)&As[(wm * 64 + mi * 16 + fr) * 32 + kb];
        #pragma unroll
        for (int ni = 0; ni < 4; ++ni)
            bv[ni] = *(const bf16x8*)&Bs[(wn * 64 + ni * 16 + fr) * 32 + kb];
        #pragma unroll
        for (int mi = 0; mi < 4; ++mi)
            #pragma unroll
            for (int ni = 0; ni < 4; ++ni)
                acc[mi][ni] = __builtin_amdgcn_mfma_f32_16x16x32_bf16(a[mi], bv[ni], acc[mi][ni], 0, 0, 0);
    }

    // epilogue: tanh + v-weighted reduce over this block's 128 s-columns
    float wqv[4], vev[4];
    #pragma unroll
    for (int ni = 0; ni < 4; ++ni) {
        const int scol = sb * 128 + wn * 64 + ni * 16 + fr;
        wqv[ni] = wq[(size_t)b * T_DIM + scol];
        vev[ni] = v_e[scol];
    }
    const int g = lane >> 4;
    #pragma unroll
    for (int mi = 0; mi < 4; ++mi) {
        #pragma unroll
        for (int rg = 0; rg < 4; ++rg) {
            float part = 0.f;
            #pragma unroll
            for (int ni = 0; ni < 4; ++ni)
                part += vev[ni] * tanhf(wqv[ni] + acc[mi][ni][rg]);
            part += __shfl_xor(part, 1);
            part += __shfl_xor(part, 2);
            part += __shfl_xor(part, 4);
            part += __shfl_xor(part, 8);
            if (fr == 0)
                atomicAdd(&sc[wm * 64 + mi * 16 + 4 * g + rg], part);
            // exactly 2 adds per slot (wn=0,1): f32 add commutative -> deterministic
        }
    }
    __syncthreads();
    if (tid < 128)
        partial[((size_t)b * 4 + sb) * N_DIM + nb * 128 + tid] = sc[tid];
}

// ---------------- fallback (round-1 verified, 3-term): used only if ws too small ----------------
__global__ __launch_bounds__(256) void fused_fallback_kernel(
    const float* __restrict__ data, const float* __restrict__ U_e,
    const float* __restrict__ v_e, const float* __restrict__ wq,
    float* __restrict__ partial)
{
#define BMf 128
#define LDKf 40
    __shared__ __align__(16) __bf16 Ah[BMf][LDKf];
    __shared__ __align__(16) __bf16 Al[BMf][LDKf];
    __shared__ __align__(16) __bf16 Bh[BMf][LDKf];
    __shared__ __align__(16) __bf16 Bl[BMf][LDKf];
    __shared__ float sc[BMf];

    const int wg = blockIdx.x;
    const int b  = wg >> 4;
    const int nb = (wg >> 2) & 3;
    const int sb = wg & 3;

    const int tid  = threadIdx.x;
    const int lane = tid & 63;
    const int wid  = tid >> 6;
    const int wm   = wid >> 1;
    const int wn   = wid & 1;

    if (tid < BMf) sc[tid] = 0.f;

    f32x4 acc[4][4];
    const f32x4 zero = {0.f, 0.f, 0.f, 0.f};
    #pragma unroll
    for (int i = 0; i < 4; ++i)
        #pragma unroll
        for (int j = 0; j < 4; ++j)
            acc[i][j] = zero;

    const float* dataB = data + (size_t)b * T_DIM * N_DIM + nb * BMf;
    const int fr = lane & 15;
    const int kb = (lane >> 4) * 8;

    for (int k0 = 0; k0 < T_DIM; k0 += 32) {
        __syncthreads();
        {
            const int k  = tid >> 3;
            const int nq = tid & 7;
            const float* src = dataB + (size_t)(k0 + k) * N_DIM;
            #pragma unroll
            for (int r = 0; r < 4; ++r) {
                const int n = (nq + r * 8) * 4;
                float4 v = *(const float4*)(src + n);
                __bf16 h, l;
                bsplit(v.x, h, l); Ah[n+0][k] = h; Al[n+0][k] = l;
                bsplit(v.y, h, l); Ah[n+1][k] = h; Al[n+1][k] = l;
                bsplit(v.z, h, l); Ah[n+2][k] = h; Al[n+2][k] = l;
                bsplit(v.w, h, l); Ah[n+3][k] = h; Al[n+3][k] = l;
            }
        }
        {
            const int s  = tid >> 1;
            const int kq = tid & 1;
            const float* src = U_e + (size_t)(sb * BMf + s) * T_DIM + k0;
            #pragma unroll
            for (int r = 0; r < 4; ++r) {
                const int k = (kq * 4 + r) * 4;
                float4 v = *(const float4*)(src + k);
                __bf16 h0,l0,h1,l1,h2,l2,h3,l3;
                bsplit(v.x, h0, l0); bsplit(v.y, h1, l1);
                bsplit(v.z, h2, l2); bsplit(v.w, h3, l3);
                Bh[s][k+0] = h0; Bh[s][k+1] = h1; Bh[s][k+2] = h2; Bh[s][k+3] = h3;
                Bl[s][k+0] = l0; Bl[s][k+1] = l1; Bl[s][k+2] = l2; Bl[s][k+3] = l3;
            }
        }
        __syncthreads();

        bf16x8 ah[4], al[4], bh[4], bl[4];
        #pragma unroll
        for (int mi = 0; mi < 4; ++mi) {
            const int row = wm * 64 + mi * 16 + fr;
            ah[mi] = *(const bf16x8*)&Ah[row][kb];
            al[mi] = *(const bf16x8*)&Al[row][kb];
        }
        #pragma unroll
        for (int ni = 0; ni < 4; ++ni) {
            const int col = wn * 64 + ni * 16 + fr;
            bh[ni] = *(const bf16x8*)&Bh[col][kb];
            bl[ni] = *(const bf16x8*)&Bl[col][kb];
        }
        #pragma unroll
        for (int mi = 0; mi < 4; ++mi)
            #pragma unroll
            for (int ni = 0; ni < 4; ++ni) {
                acc[mi][ni] = __builtin_amdgcn_mfma_f32_16x16x32_bf16(ah[mi], bh[ni], acc[mi][ni], 0, 0, 0);
                acc[mi][ni] = __builtin_amdgcn_mfma_f32_16x16x32_bf16(al[mi], bh[ni], acc[mi][ni], 0, 0, 0);
                acc[mi][ni] = __builtin_amdgcn_mfma_f32_16x16x32_bf16(ah[mi], bl[ni], acc[mi][ni], 0, 0, 0);
            }
    }

    float wqv[4], vev[4];
    #pragma unroll
    for (int ni = 0; ni < 4; ++ni) {
        const int scol = sb * BMf + wn * 64 + ni * 16 + fr;
        wqv[ni] = wq[(size_t)b * T_DIM + scol];
        vev[ni] = v_e[scol];
    }
    const int g = lane >> 4;
    #pragma unroll
    for (int mi = 0; mi < 4; ++mi) {
        #pragma unroll
        for (int rg = 0; rg < 4; ++rg) {
            float part = 0.f;
            #pragma unroll
            for (int ni = 0; ni < 4; ++ni)
                part += vev[ni] * tanhf(wqv[ni] + acc[mi][ni][rg]);
            part += __shfl_xor(part, 1);
            part += __shfl_xor(part, 2);
            part += __shfl_xor(part, 4);
            part += __shfl_xor(part, 8);
            if (fr == 0)
                atomicAdd(&sc[wm * 64 + mi * 16 + 4 * g + rg], part);
        }
    }
    __syncthreads();
    if (tid < BMf)
        partial[((size_t)b * 4 + sb) * N_DIM + nb * BMf + tid] = sc[tid];
}

// ---------------- softmax ----------------
__global__ __launch_bounds__(512) void softmax_kernel(
    const float* __restrict__ partial, float* __restrict__ out)
{
    const int b = blockIdx.x;
    const int n = threadIdx.x;
    const float* p = partial + (size_t)b * 4 * N_DIM;
    float s = p[n] + p[N_DIM + n] + p[2 * N_DIM + n] + p[3 * N_DIM + n];

    float m = s;
    #pragma unroll
    for (int off = 1; off < 64; off <<= 1)
        m = fmaxf(m, __shfl_xor(m, off));
    __shared__ float red[8];
    const int wv = n >> 6;
    if ((n & 63) == 0) red[wv] = m;
    __syncthreads();
    float bm = red[0];
    #pragma unroll
    for (int i = 1; i < 8; ++i) bm = fmaxf(bm, red[i]);

    float e = expf(s - bm);
    float t = e;
    #pragma unroll
    for (int off = 1; off < 64; off <<= 1)
        t += __shfl_xor(t, off);
    __syncthreads();
    if ((n & 63) == 0) red[wv] = t;
    __syncthreads();
    float tot = 0.f;
    #pragma unroll
    for (int i = 0; i < 8; ++i) tot += red[i];

    out[(size_t)b * N_DIM + n] = e / tot;
}

extern "C" void kernel_launch(void* const* d_in, const int* in_sizes, int n_in,
                              void* d_out, int out_size, void* d_ws, size_t ws_size,
                              hipStream_t stream) {
    const float* h_t  = (const float*)d_in[0];
    const float* s_t  = (const float*)d_in[1];
    const float* data = (const float*)d_in[2];
    const float* W_e  = (const float*)d_in[3];
    const float* U_e  = (const float*)d_in[4];
    const float* v_e  = (const float*)d_in[5];
    float* out = (float*)d_out;

    const size_t wq_elems      = (size_t)B_DIM * T_DIM;            // f32
    const size_t partial_elems = (size_t)B_DIM * 4 * N_DIM;        // f32
    const size_t u_elems       = (size_t)T_DIM * T_DIM;            // bf16
    const size_t dT_elems      = (size_t)B_DIM * N_DIM * T_DIM;    // bf16

    float* wq      = (float*)d_ws;
    float* partial = wq + wq_elems;
    __bf16* Uh     = (__bf16*)(partial + partial_elems);
    __bf16* dataT  = Uh + u_elems;

    const size_t need = (wq_elems + partial_elems) * 4 + (u_elems + dT_elems) * 2;

    wq_kernel<<<B_DIM, 256, 0, stream>>>(h_t, s_t, W_e, wq);
    if (ws_size >= need) {
        uconv_kernel<<<(int)(u_elems / 512), 256, 0, stream>>>(U_e, Uh);
        transpose_kernel<<<B_DIM * 64, 256, 0, stream>>>(data, dataT);
        fused1_kernel<<<B_DIM * 16, 256, 0, stream>>>(dataT, Uh, v_e, wq, partial);
    } else {
        fused_fallback_kernel<<<B_DIM * 16, 256, 0, stream>>>(data, U_e, v_e, wq, partial);
    }
    softmax_kernel<<<B_DIM, 512, 0, stream>>>(partial, out);
}

// Round 4
// 234.647 us; speedup vs baseline: 1.6392x; 1.0327x over previous
//
#include <hip/hip_runtime.h>
#include <hip/hip_bf16.h>
#include <cmath>

#define T_DIM 512
#define N_DIM 512
#define M_DIM 256
#define B_DIM 256

typedef __bf16 bf16x8 __attribute__((ext_vector_type(8)));
typedef float  f32x4  __attribute__((ext_vector_type(4)));
typedef unsigned int u32;

__device__ __forceinline__ void gload16(const __bf16* g, __bf16* l) {
    __builtin_amdgcn_global_load_lds(
        (const __attribute__((address_space(1))) void*)g,
        (__attribute__((address_space(3))) void*)l, 16, 0, 0);
}

// ---------------- precompute: U_e -> bf16 ----------------
__global__ __launch_bounds__(256) void uconv_kernel(
    const float* __restrict__ U, __bf16* __restrict__ Uh)
{
    const int i = (blockIdx.x * 256 + threadIdx.x) * 2;
    float2 v = *(const float2*)(U + i);
    Uh[i]   = (__bf16)v.x;
    Uh[i+1] = (__bf16)v.y;
}

// ---------------- wq[b,t] = concat(h,s) . W_e[t,:] ----------------
__global__ __launch_bounds__(256) void wq_kernel(
    const float* __restrict__ h_t, const float* __restrict__ s_t,
    const float* __restrict__ W_e, float* __restrict__ wq)
{
    __shared__ float q[2 * M_DIM];
    const int b = blockIdx.x;
    const int tid = threadIdx.x;
    q[tid]         = h_t[(size_t)b * M_DIM + tid];
    q[M_DIM + tid] = s_t[(size_t)b * M_DIM + tid];
    __syncthreads();
    for (int tt = tid; tt < T_DIM; tt += 256) {
        const float4* wrow = (const float4*)(W_e + (size_t)tt * (2 * M_DIM));
        float acc = 0.f;
        #pragma unroll 4
        for (int k4 = 0; k4 < (2 * M_DIM) / 4; ++k4) {
            float4 w = wrow[k4];
            acc += q[4*k4+0] * w.x + q[4*k4+1] * w.y
                 + q[4*k4+2] * w.z + q[4*k4+3] * w.w;
        }
        wq[(size_t)b * T_DIM + tt] = acc;
    }
}

// ---------------- fused: in-kernel A-transpose + GEMM + tanh + v-dot ----------------
// Tile per wg: C[128 n][256 s], K = 512 (t). 4 waves (2 n-halves x 2 s-halves).
// A = data[b, t, nb*128 + n] (f32, reg-staged transpose -> LDS bf16 [n][t]).
// B = Uh[sh*256 + s, t]      (bf16, k-contiguous -> global_load_lds).
__global__ __launch_bounds__(256, 2) void fused3_kernel(
    const float* __restrict__ data, const __bf16* __restrict__ Uh,
    const float* __restrict__ v_e, const float* __restrict__ wq,
    float* __restrict__ partial)
{
    __shared__ __align__(16) __bf16 As[128 * 32];   // [n][t], 64 B rows
    __shared__ __align__(16) __bf16 Bs[256 * 32];   // [s][t]
    __shared__ float sc[128];

    // XCD-aware decode: both sh-halves of a (b,nb) pair land on the same XCD
    // (default dispatch round-robins wg%8 across the 8 XCDs) -> data L2 reuse.
    const int wg    = blockIdx.x;
    const int xcd   = wg & 7;
    const int local = wg >> 3;           // 0..255 per XCD
    const int sh    = local & 1;
    const int p     = xcd + 8 * (local >> 1);   // (b,nb) pair id, bijective over [0,1024)
    const int b     = p >> 2;
    const int nb    = p & 3;

    const int tid  = threadIdx.x;
    const int lane = tid & 63;
    const int wid  = tid >> 6;
    const int wm   = wid >> 1;           // n-half
    const int wn   = wid & 1;            // s-half

    if (tid < 128) sc[tid] = 0.f;

    f32x4 acc[4][8];
    const f32x4 zero = {0.f, 0.f, 0.f, 0.f};
    #pragma unroll
    for (int i = 0; i < 4; ++i)
        #pragma unroll
        for (int j = 0; j < 8; ++j)
            acc[i][j] = zero;

    const float*  Ab = data + (size_t)b * T_DIM * N_DIM + nb * 128;
    const __bf16* Bb = Uh + (size_t)(sh * 256) * T_DIM;

    // A staging: thread handles t-pair tp (t = 2*tp, 2*tp+1), n-range [n0, n0+8)
    const int tp = tid & 15;
    const int n0 = (tid >> 4) * 8;
    u32* As32 = (u32*)As;                // [n][16] u32 per row

    // B staging: 4 x gload_lds, rows r0 + 64i, 16B chunk ce
    const int r0 = tid >> 2;
    const int ce = (tid & 3) * 8;
    __bf16* lB = &Bs[tid * 8];

    const int fr = lane & 15;
    const int kb = (lane >> 4) * 8;

    // prologue: prefetch A f32 regs for k0 = 0
    const float* s0 = Ab + (size_t)(2 * tp) * N_DIM + n0;
    float4 pa0 = *(const float4*)s0;
    float4 pa1 = *(const float4*)(s0 + 4);
    float4 pa2 = *(const float4*)(s0 + N_DIM);
    float4 pa3 = *(const float4*)(s0 + N_DIM + 4);

    for (int k0 = 0; k0 < T_DIM; k0 += 32) {
        __syncthreads();                 // previous tile fully consumed
        // B: global -> LDS direct
        #pragma unroll
        for (int i = 0; i < 4; ++i)
            gload16(Bb + (size_t)(i * 64 + r0) * T_DIM + k0 + ce, lB + i * 64 * 32);

        // A: convert current regs, write transposed (pack t,t+1 per n)
        {
            const float lo_[8] = {pa0.x, pa0.y, pa0.z, pa0.w, pa1.x, pa1.y, pa1.z, pa1.w};
            const float hi_[8] = {pa2.x, pa2.y, pa2.z, pa2.w, pa3.x, pa3.y, pa3.z, pa3.w};
            #pragma unroll
            for (int j = 0; j < 8; ++j) {
                __bf16 l = (__bf16)lo_[j];
                __bf16 h = (__bf16)hi_[j];
                u32 w = ((u32)__builtin_bit_cast(unsigned short, h) << 16)
                      |  (u32)__builtin_bit_cast(unsigned short, l);
                As32[(n0 + j) * 16 + tp] = w;
            }
        }
        // prefetch A regs for next k-step
        if (k0 + 32 < T_DIM) {
            const float* sn = Ab + (size_t)(k0 + 32 + 2 * tp) * N_DIM + n0;
            pa0 = *(const float4*)sn;
            pa1 = *(const float4*)(sn + 4);
            pa2 = *(const float4*)(sn + N_DIM);
            pa3 = *(const float4*)(sn + N_DIM + 4);
        }
        __syncthreads();                 // drains B gloads + A ds_writes

        bf16x8 a[4], bv[8];
        #pragma unroll
        for (int mi = 0; mi < 4; ++mi)
            a[mi] = *(const bf16x8*)&As[(wm * 64 + mi * 16 + fr) * 32 + kb];
        #pragma unroll
        for (int ni = 0; ni < 8; ++ni)
            bv[ni] = *(const bf16x8*)&Bs[(wn * 128 + ni * 16 + fr) * 32 + kb];
        #pragma unroll
        for (int mi = 0; mi < 4; ++mi)
            #pragma unroll
            for (int ni = 0; ni < 8; ++ni)
                acc[mi][ni] = __builtin_amdgcn_mfma_f32_16x16x32_bf16(a[mi], bv[ni], acc[mi][ni], 0, 0, 0);
    }

    // epilogue: tanh + v-weighted reduce over this wave's 128 s-columns
    float wqv[8], vev[8];
    #pragma unroll
    for (int ni = 0; ni < 8; ++ni) {
        const int scol = sh * 256 + wn * 128 + ni * 16 + fr;
        wqv[ni] = wq[(size_t)b * T_DIM + scol];
        vev[ni] = v_e[scol];
    }
    const int g = lane >> 4;
    #pragma unroll
    for (int mi = 0; mi < 4; ++mi) {
        #pragma unroll
        for (int rg = 0; rg < 4; ++rg) {
            float part = 0.f;
            #pragma unroll
            for (int ni = 0; ni < 8; ++ni)
                part += vev[ni] * tanhf(wqv[ni] + acc[mi][ni][rg]);
            part += __shfl_xor(part, 1);
            part += __shfl_xor(part, 2);
            part += __shfl_xor(part, 4);
            part += __shfl_xor(part, 8);
            if (fr == 0)
                atomicAdd(&sc[wm * 64 + mi * 16 + 4 * g + rg], part);
            // exactly 2 adds per slot (wn=0,1): f32 add commutative -> deterministic
        }
    }
    __syncthreads();
    if (tid < 128)
        partial[((size_t)b * 2 + sh) * N_DIM + nb * 128 + tid] = sc[tid];
}

// ---------------- softmax over n (sums the 2 s-half partials) ----------------
__global__ __launch_bounds__(512) void softmax_kernel(
    const float* __restrict__ partial, float* __restrict__ out)
{
    const int b = blockIdx.x;
    const int n = threadIdx.x;
    const float* p = partial + (size_t)b * 2 * N_DIM;
    float s = p[n] + p[N_DIM + n];

    float m = s;
    #pragma unroll
    for (int off = 1; off < 64; off <<= 1)
        m = fmaxf(m, __shfl_xor(m, off));
    __shared__ float red[8];
    const int wv = n >> 6;
    if ((n & 63) == 0) red[wv] = m;
    __syncthreads();
    float bm = red[0];
    #pragma unroll
    for (int i = 1; i < 8; ++i) bm = fmaxf(bm, red[i]);

    float e = expf(s - bm);
    float t = e;
    #pragma unroll
    for (int off = 1; off < 64; off <<= 1)
        t += __shfl_xor(t, off);
    __syncthreads();
    if ((n & 63) == 0) red[wv] = t;
    __syncthreads();
    float tot = 0.f;
    #pragma unroll
    for (int i = 0; i < 8; ++i) tot += red[i];

    out[(size_t)b * N_DIM + n] = e / tot;
}

extern "C" void kernel_launch(void* const* d_in, const int* in_sizes, int n_in,
                              void* d_out, int out_size, void* d_ws, size_t ws_size,
                              hipStream_t stream) {
    const float* h_t  = (const float*)d_in[0];
    const float* s_t  = (const float*)d_in[1];
    const float* data = (const float*)d_in[2];
    const float* W_e  = (const float*)d_in[3];
    const float* U_e  = (const float*)d_in[4];
    const float* v_e  = (const float*)d_in[5];
    float* out = (float*)d_out;

    const size_t wq_elems      = (size_t)B_DIM * T_DIM;         // f32
    const size_t partial_elems = (size_t)B_DIM * 2 * N_DIM;     // f32
    const size_t u_elems       = (size_t)T_DIM * T_DIM;         // bf16

    float* wq      = (float*)d_ws;
    float* partial = wq + wq_elems;
    __bf16* Uh     = (__bf16*)(partial + partial_elems);

    wq_kernel<<<B_DIM, 256, 0, stream>>>(h_t, s_t, W_e, wq);
    uconv_kernel<<<(int)(u_elems / 512), 256, 0, stream>>>(U_e, Uh);
    fused3_kernel<<<B_DIM * 8, 256, 0, stream>>>(data, Uh, v_e, wq, partial);
    softmax_kernel<<<B_DIM, 512, 0, stream>>>(partial, out);
}

// Round 5
// 179.944 us; speedup vs baseline: 2.1375x; 1.3040x over previous
//
#include <hip/hip_runtime.h>
#include <hip/hip_bf16.h>
#include <cmath>

#define T_DIM 512
#define N_DIM 512
#define M_DIM 256
#define B_DIM 256

typedef __bf16 bf16x8 __attribute__((ext_vector_type(8)));
typedef float  f32x4  __attribute__((ext_vector_type(4)));
typedef unsigned int u32;

__device__ __forceinline__ void gload16(const __bf16* g, __bf16* l) {
    __builtin_amdgcn_global_load_lds(
        (const __attribute__((address_space(1))) void*)g,
        (__attribute__((address_space(3))) void*)l, 16, 0, 0);
}

// ---------------- precompute: U_e -> bf16 ----------------
__global__ __launch_bounds__(256) void uconv_kernel(
    const float* __restrict__ U, __bf16* __restrict__ Uh)
{
    const int i = (blockIdx.x * 256 + threadIdx.x) * 2;
    float2 v = *(const float2*)(U + i);
    Uh[i]   = (__bf16)v.x;
    Uh[i+1] = (__bf16)v.y;
}

// ---------------- wq[b,t] = concat(h,s) . W_e[t,:] ----------------
__global__ __launch_bounds__(256) void wq_kernel(
    const float* __restrict__ h_t, const float* __restrict__ s_t,
    const float* __restrict__ W_e, float* __restrict__ wq)
{
    __shared__ float q[2 * M_DIM];
    const int b = blockIdx.x;
    const int tid = threadIdx.x;
    q[tid]         = h_t[(size_t)b * M_DIM + tid];
    q[M_DIM + tid] = s_t[(size_t)b * M_DIM + tid];
    __syncthreads();
    for (int tt = tid; tt < T_DIM; tt += 256) {
        const float4* wrow = (const float4*)(W_e + (size_t)tt * (2 * M_DIM));
        float acc = 0.f;
        #pragma unroll 4
        for (int k4 = 0; k4 < (2 * M_DIM) / 4; ++k4) {
            float4 w = wrow[k4];
            acc += q[4*k4+0] * w.x + q[4*k4+1] * w.y
                 + q[4*k4+2] * w.z + q[4*k4+3] * w.w;
        }
        wq[(size_t)b * T_DIM + tt] = acc;
    }
}

// ---------------- fused: in-kernel A-transpose + GEMM + tanh + v-dot ----------------
// Tile per wg: C[128 n][256 s], K = 512 (t). 4 waves (2 n-halves x 2 s-halves).
// A staging: COALESCED loads (consecutive lanes -> consecutive n), transpose-write
// into LDS with 16B-granular XOR swizzle (write 4-way instead of 16-way conflict).
__global__ __launch_bounds__(256, 2) void fused3_kernel(
    const float* __restrict__ data, const __bf16* __restrict__ Uh,
    const float* __restrict__ v_e, const float* __restrict__ wq,
    float* __restrict__ partial)
{
    __shared__ __align__(16) __bf16 As[128 * 32];   // [n][t], 64 B rows, swizzled blocks
    __shared__ __align__(16) __bf16 Bs[256 * 32];   // [s][t], linear (gload_lds)
    __shared__ float sc[128];

    // XCD-aware decode: both sh-halves of a (b,nb) pair land on the same XCD.
    const int wg    = blockIdx.x;
    const int xcd   = wg & 7;
    const int local = wg >> 3;
    const int sh    = local & 1;
    const int p     = xcd + 8 * (local >> 1);   // bijective over [0,1024)
    const int b     = p >> 2;
    const int nb    = p & 3;

    const int tid  = threadIdx.x;
    const int lane = tid & 63;
    const int wid  = tid >> 6;
    const int wm   = wid >> 1;           // n-half
    const int wn   = wid & 1;            // s-half

    if (tid < 128) sc[tid] = 0.f;

    f32x4 acc[4][8];
    const f32x4 zero = {0.f, 0.f, 0.f, 0.f};
    #pragma unroll
    for (int i = 0; i < 4; ++i)
        #pragma unroll
        for (int j = 0; j < 8; ++j)
            acc[i][j] = zero;

    const float*  Ab = data + (size_t)b * T_DIM * N_DIM + nb * 128;
    const __bf16* Bb = Uh + (size_t)(sh * 256) * T_DIM;

    // A staging: rp = row-pair (t = 2rp, 2rp+1), cg = col-group (n = 8cg..8cg+7).
    // Consecutive 16 lanes (same rp) cover 512 contiguous bytes per row.
    const int rp = tid >> 4;
    const int cg = tid & 15;
    const int n0 = cg * 8;
    const int swzk = (cg & 3) << 2;      // XOR key, u32-index bits 2-3 (byte bits 4-5)
    u32* As32 = (u32*)As;                // [n][16] u32 per row

    // B staging: 4 x gload_lds, linear dest
    const int r0 = tid >> 2;
    const int ce = (tid & 3) * 8;
    __bf16* lB = &Bs[tid * 8];

    const int fr = lane & 15;
    const int kb = (lane >> 4) * 8;

    // A-fragment read offsets (swizzled to match the write): elem key = byte key >> 1
    int aoff[4];
    #pragma unroll
    for (int mi = 0; mi < 4; ++mi) {
        const int row = wm * 64 + mi * 16 + fr;
        aoff[mi] = (row * 32 + kb) ^ (((row >> 3) & 3) << 3);
    }

    // prologue: prefetch A f32 regs for k0 = 0
    const float* s0 = Ab + (size_t)(2 * rp) * N_DIM + n0;
    float4 pa0 = *(const float4*)s0;
    float4 pa1 = *(const float4*)(s0 + 4);
    float4 pa2 = *(const float4*)(s0 + N_DIM);
    float4 pa3 = *(const float4*)(s0 + N_DIM + 4);

    for (int k0 = 0; k0 < T_DIM; k0 += 32) {
        __syncthreads();                 // previous tile fully consumed
        // B: global -> LDS direct
        #pragma unroll
        for (int i = 0; i < 4; ++i)
            gload16(Bb + (size_t)(i * 64 + r0) * T_DIM + k0 + ce, lB + i * 64 * 32);

        // A: convert prefetched regs, swizzled transpose-write (t,t+1 packed per n)
        {
            const float lo_[8] = {pa0.x, pa0.y, pa0.z, pa0.w, pa1.x, pa1.y, pa1.z, pa1.w};
            const float hi_[8] = {pa2.x, pa2.y, pa2.z, pa2.w, pa3.x, pa3.y, pa3.z, pa3.w};
            #pragma unroll
            for (int j = 0; j < 8; ++j) {
                __bf16 l = (__bf16)lo_[j];
                __bf16 h = (__bf16)hi_[j];
                u32 w = ((u32)__builtin_bit_cast(unsigned short, h) << 16)
                      |  (u32)__builtin_bit_cast(unsigned short, l);
                As32[((n0 + j) * 16 + rp) ^ swzk] = w;
            }
        }
        __syncthreads();                 // drains B gloads + A ds_writes

        // prefetch A regs for next k-step: issued AFTER the barrier so the
        // vmcnt(0) drain at the NEXT barrier hides them under this MFMA section
        if (k0 + 32 < T_DIM) {
            const float* sn = Ab + (size_t)(k0 + 32 + 2 * rp) * N_DIM + n0;
            pa0 = *(const float4*)sn;
            pa1 = *(const float4*)(sn + 4);
            pa2 = *(const float4*)(sn + N_DIM);
            pa3 = *(const float4*)(sn + N_DIM + 4);
        }

        bf16x8 a[4], bv[8];
        #pragma unroll
        for (int mi = 0; mi < 4; ++mi)
            a[mi] = *(const bf16x8*)&As[aoff[mi]];
        #pragma unroll
        for (int ni = 0; ni < 8; ++ni)
            bv[ni] = *(const bf16x8*)&Bs[(wn * 128 + ni * 16 + fr) * 32 + kb];
        #pragma unroll
        for (int mi = 0; mi < 4; ++mi)
            #pragma unroll
            for (int ni = 0; ni < 8; ++ni)
                acc[mi][ni] = __builtin_amdgcn_mfma_f32_16x16x32_bf16(a[mi], bv[ni], acc[mi][ni], 0, 0, 0);
    }

    // epilogue: tanh + v-weighted reduce over this wave's 128 s-columns
    float wqv[8], vev[8];
    #pragma unroll
    for (int ni = 0; ni < 8; ++ni) {
        const int scol = sh * 256 + wn * 128 + ni * 16 + fr;
        wqv[ni] = wq[(size_t)b * T_DIM + scol];
        vev[ni] = v_e[scol];
    }
    const int g = lane >> 4;
    #pragma unroll
    for (int mi = 0; mi < 4; ++mi) {
        #pragma unroll
        for (int rg = 0; rg < 4; ++rg) {
            float part = 0.f;
            #pragma unroll
            for (int ni = 0; ni < 8; ++ni)
                part += vev[ni] * tanhf(wqv[ni] + acc[mi][ni][rg]);
            part += __shfl_xor(part, 1);
            part += __shfl_xor(part, 2);
            part += __shfl_xor(part, 4);
            part += __shfl_xor(part, 8);
            if (fr == 0)
                atomicAdd(&sc[wm * 64 + mi * 16 + 4 * g + rg], part);
            // exactly 2 adds per slot (wn=0,1): f32 add commutative -> deterministic
        }
    }
    __syncthreads();
    if (tid < 128)
        partial[((size_t)b * 2 + sh) * N_DIM + nb * 128 + tid] = sc[tid];
}

// ---------------- softmax over n (sums the 2 s-half partials) ----------------
__global__ __launch_bounds__(512) void softmax_kernel(
    const float* __restrict__ partial, float* __restrict__ out)
{
    const int b = blockIdx.x;
    const int n = threadIdx.x;
    const float* p = partial + (size_t)b * 2 * N_DIM;
    float s = p[n] + p[N_DIM + n];

    float m = s;
    #pragma unroll
    for (int off = 1; off < 64; off <<= 1)
        m = fmaxf(m, __shfl_xor(m, off));
    __shared__ float red[8];
    const int wv = n >> 6;
    if ((n & 63) == 0) red[wv] = m;
    __syncthreads();
    float bm = red[0];
    #pragma unroll
    for (int i = 1; i < 8; ++i) bm = fmaxf(bm, red[i]);

    float e = expf(s - bm);
    float t = e;
    #pragma unroll
    for (int off = 1; off < 64; off <<= 1)
        t += __shfl_xor(t, off);
    __syncthreads();
    if ((n & 63) == 0) red[wv] = t;
    __syncthreads();
    float tot = 0.f;
    #pragma unroll
    for (int i = 0; i < 8; ++i) tot += red[i];

    out[(size_t)b * N_DIM + n] = e / tot;
}

extern "C" void kernel_launch(void* const* d_in, const int* in_sizes, int n_in,
                              void* d_out, int out_size, void* d_ws, size_t ws_size,
                              hipStream_t stream) {
    const float* h_t  = (const float*)d_in[0];
    const float* s_t  = (const float*)d_in[1];
    const float* data = (const float*)d_in[2];
    const float* W_e  = (const float*)d_in[3];
    const float* U_e  = (const float*)d_in[4];
    const float* v_e  = (const float*)d_in[5];
    float* out = (float*)d_out;

    const size_t wq_elems      = (size_t)B_DIM * T_DIM;         // f32
    const size_t partial_elems = (size_t)B_DIM * 2 * N_DIM;     // f32
    const size_t u_elems       = (size_t)T_DIM * T_DIM;         // bf16

    float* wq      = (float*)d_ws;
    float* partial = wq + wq_elems;
    __bf16* Uh     = (__bf16*)(partial + partial_elems);

    wq_kernel<<<B_DIM, 256, 0, stream>>>(h_t, s_t, W_e, wq);
    uconv_kernel<<<(int)(u_elems / 512), 256, 0, stream>>>(U_e, Uh);
    fused3_kernel<<<B_DIM * 8, 256, 0, stream>>>(data, Uh, v_e, wq, partial);
    softmax_kernel<<<B_DIM, 512, 0, stream>>>(partial, out);
}

// Round 6
// 176.196 us; speedup vs baseline: 2.1830x; 1.0213x over previous
//
#include <hip/hip_runtime.h>
#include <hip/hip_bf16.h>
#include <cmath>

#define T_DIM 512
#define N_DIM 512
#define M_DIM 256
#define B_DIM 256

typedef __bf16 bf16x8 __attribute__((ext_vector_type(8)));
typedef float  f32x4  __attribute__((ext_vector_type(4)));
typedef unsigned int u32;

__device__ __forceinline__ void gload16(const __bf16* g, __bf16* l) {
    __builtin_amdgcn_global_load_lds(
        (const __attribute__((address_space(1))) void*)g,
        (__attribute__((address_space(3))) void*)l, 16, 0, 0);
}

// ---------------- precompute: U_e -> bf16 ----------------
__global__ __launch_bounds__(256) void uconv_kernel(
    const float* __restrict__ U, __bf16* __restrict__ Uh)
{
    const int i = (blockIdx.x * 256 + threadIdx.x) * 2;
    float2 v = *(const float2*)(U + i);
    Uh[i]   = (__bf16)v.x;
    Uh[i+1] = (__bf16)v.y;
}

// ---------------- wq[b,t] = concat(h,s) . W_e[t,:] ----------------
__global__ __launch_bounds__(256) void wq_kernel(
    const float* __restrict__ h_t, const float* __restrict__ s_t,
    const float* __restrict__ W_e, float* __restrict__ wq)
{
    __shared__ float q[2 * M_DIM];
    const int b = blockIdx.x;
    const int tid = threadIdx.x;
    q[tid]         = h_t[(size_t)b * M_DIM + tid];
    q[M_DIM + tid] = s_t[(size_t)b * M_DIM + tid];
    __syncthreads();
    for (int tt = tid; tt < T_DIM; tt += 256) {
        const float4* wrow = (const float4*)(W_e + (size_t)tt * (2 * M_DIM));
        float acc = 0.f;
        #pragma unroll 4
        for (int k4 = 0; k4 < (2 * M_DIM) / 4; ++k4) {
            float4 w = wrow[k4];
            acc += q[4*k4+0] * w.x + q[4*k4+1] * w.y
                 + q[4*k4+2] * w.z + q[4*k4+3] * w.w;
        }
        wq[(size_t)b * T_DIM + tt] = acc;
    }
}

// ---------------- fused: in-kernel A-transpose + GEMM + tanh + v-dot ----------------
// Tile per wg: C[128 n][256 s], K = 512 (t). 4 waves (2 n-halves x 2 s-halves).
// Double-buffered LDS, ONE barrier per K-step: stage(k+1) issued before MFMA(k),
// so gloads/prefetch latency hides under ds_read + 32 MFMA.
__global__ __launch_bounds__(256, 2) void fused4_kernel(
    const float* __restrict__ data, const __bf16* __restrict__ Uh,
    const float* __restrict__ v_e, const float* __restrict__ wq,
    float* __restrict__ partial)
{
    __shared__ __align__(16) __bf16 As[2][128 * 32];   // [n][t], swizzled blocks
    __shared__ __align__(16) __bf16 Bs[2][256 * 32];   // [s][t], linear (gload_lds)
    __shared__ float sc[128];

    // XCD-aware decode: both sh-halves of a (b,nb) pair land on the same XCD.
    const int wg    = blockIdx.x;
    const int xcd   = wg & 7;
    const int local = wg >> 3;
    const int sh    = local & 1;
    const int p     = xcd + 8 * (local >> 1);   // bijective over [0,1024)
    const int b     = p >> 2;
    const int nb    = p & 3;

    const int tid  = threadIdx.x;
    const int lane = tid & 63;
    const int wid  = tid >> 6;
    const int wm   = wid >> 1;           // n-half
    const int wn   = wid & 1;            // s-half

    if (tid < 128) sc[tid] = 0.f;

    f32x4 acc[4][8];
    const f32x4 zero = {0.f, 0.f, 0.f, 0.f};
    #pragma unroll
    for (int i = 0; i < 4; ++i)
        #pragma unroll
        for (int j = 0; j < 8; ++j)
            acc[i][j] = zero;

    const float*  Ab = data + (size_t)b * T_DIM * N_DIM + nb * 128;
    const __bf16* Bb = Uh + (size_t)(sh * 256) * T_DIM;

    // A staging: rp = t-pair row, cg = n col-group; 16 lanes = 512 contiguous bytes.
    const int rp = tid >> 4;
    const int cg = tid & 15;
    const int n0 = cg * 8;
    const int swzk = (cg & 3) << 2;      // XOR key on u32-index bits 2-3

    // B staging: 4 x gload_lds, linear dest
    const int r0 = tid >> 2;
    const int ce = (tid & 3) * 8;

    const int fr = lane & 15;
    const int kb = (lane >> 4) * 8;

    // A-fragment read offsets (match write swizzle)
    int aoff[4];
    #pragma unroll
    for (int mi = 0; mi < 4; ++mi) {
        const int row = wm * 64 + mi * 16 + fr;
        aoff[mi] = (row * 32 + kb) ^ (((row >> 3) & 3) << 3);
    }
    int boff[8];
    #pragma unroll
    for (int ni = 0; ni < 8; ++ni)
        boff[ni] = (wn * 128 + ni * 16 + fr) * 32 + kb;

    // ---- prologue: stage tile 0 into buf 0, prefetch A regs for tile 1
    const float* s0 = Ab + (size_t)(2 * rp) * N_DIM + n0;
    float4 pa0 = *(const float4*)s0;
    float4 pa1 = *(const float4*)(s0 + 4);
    float4 pa2 = *(const float4*)(s0 + N_DIM);
    float4 pa3 = *(const float4*)(s0 + N_DIM + 4);

    #pragma unroll
    for (int i = 0; i < 4; ++i)
        gload16(Bb + (size_t)(i * 64 + r0) * T_DIM + ce, &Bs[0][tid * 8] + i * 64 * 32);
    {
        u32* As32 = (u32*)As[0];
        const float lo_[8] = {pa0.x, pa0.y, pa0.z, pa0.w, pa1.x, pa1.y, pa1.z, pa1.w};
        const float hi_[8] = {pa2.x, pa2.y, pa2.z, pa2.w, pa3.x, pa3.y, pa3.z, pa3.w};
        #pragma unroll
        for (int j = 0; j < 8; ++j) {
            __bf16 l = (__bf16)lo_[j];
            __bf16 h = (__bf16)hi_[j];
            u32 w = ((u32)__builtin_bit_cast(unsigned short, h) << 16)
                  |  (u32)__builtin_bit_cast(unsigned short, l);
            As32[((n0 + j) * 16 + rp) ^ swzk] = w;
        }
    }
    {
        const float* sn = Ab + (size_t)(32 + 2 * rp) * N_DIM + n0;
        pa0 = *(const float4*)sn;
        pa1 = *(const float4*)(sn + 4);
        pa2 = *(const float4*)(sn + N_DIM);
        pa3 = *(const float4*)(sn + N_DIM + 4);
    }
    __syncthreads();

    int cur = 0;
    for (int k0 = 0; k0 < T_DIM; k0 += 32) {
        // ---- fragment reads from buf[cur] FIRST (MFMA waits only on these)
        bf16x8 a[4], bv[8];
        #pragma unroll
        for (int mi = 0; mi < 4; ++mi)
            a[mi] = *(const bf16x8*)&As[cur][aoff[mi]];
        #pragma unroll
        for (int ni = 0; ni < 8; ++ni)
            bv[ni] = *(const bf16x8*)&Bs[cur][boff[ni]];

        // ---- stage tile k+1 into buf[cur^1] (overlaps with MFMA below)
        if (k0 + 32 < T_DIM) {
            const int nxt = cur ^ 1;
            #pragma unroll
            for (int i = 0; i < 4; ++i)
                gload16(Bb + (size_t)(i * 64 + r0) * T_DIM + (k0 + 32) + ce,
                        &Bs[nxt][tid * 8] + i * 64 * 32);
            u32* As32 = (u32*)As[nxt];
            const float lo_[8] = {pa0.x, pa0.y, pa0.z, pa0.w, pa1.x, pa1.y, pa1.z, pa1.w};
            const float hi_[8] = {pa2.x, pa2.y, pa2.z, pa2.w, pa3.x, pa3.y, pa3.z, pa3.w};
            #pragma unroll
            for (int j = 0; j < 8; ++j) {
                __bf16 l = (__bf16)lo_[j];
                __bf16 h = (__bf16)hi_[j];
                u32 w = ((u32)__builtin_bit_cast(unsigned short, h) << 16)
                      |  (u32)__builtin_bit_cast(unsigned short, l);
                As32[((n0 + j) * 16 + rp) ^ swzk] = w;
            }
            if (k0 + 64 < T_DIM) {
                const float* sn = Ab + (size_t)(k0 + 64 + 2 * rp) * N_DIM + n0;
                pa0 = *(const float4*)sn;
                pa1 = *(const float4*)(sn + 4);
                pa2 = *(const float4*)(sn + N_DIM);
                pa3 = *(const float4*)(sn + N_DIM + 4);
            }
        }

        // ---- MFMA on tile k
        #pragma unroll
        for (int mi = 0; mi < 4; ++mi)
            #pragma unroll
            for (int ni = 0; ni < 8; ++ni)
                acc[mi][ni] = __builtin_amdgcn_mfma_f32_16x16x32_bf16(a[mi], bv[ni], acc[mi][ni], 0, 0, 0);

        __syncthreads();   // drains stage ops; buf[cur^1] ready for next iter
        cur ^= 1;
    }

    // ---- epilogue: tanh + v-weighted reduce over this wave's 128 s-columns
    float wqv[8], vev[8];
    #pragma unroll
    for (int ni = 0; ni < 8; ++ni) {
        const int scol = sh * 256 + wn * 128 + ni * 16 + fr;
        wqv[ni] = wq[(size_t)b * T_DIM + scol];
        vev[ni] = v_e[scol];
    }
    const int g = lane >> 4;
    #pragma unroll
    for (int mi = 0; mi < 4; ++mi) {
        #pragma unroll
        for (int rg = 0; rg < 4; ++rg) {
            float part = 0.f;
            #pragma unroll
            for (int ni = 0; ni < 8; ++ni)
                part += vev[ni] * tanhf(wqv[ni] + acc[mi][ni][rg]);
            part += __shfl_xor(part, 1);
            part += __shfl_xor(part, 2);
            part += __shfl_xor(part, 4);
            part += __shfl_xor(part, 8);
            if (fr == 0)
                atomicAdd(&sc[wm * 64 + mi * 16 + 4 * g + rg], part);
            // exactly 2 adds per slot (wn=0,1): f32 add commutative -> deterministic
        }
    }
    __syncthreads();
    if (tid < 128)
        partial[((size_t)b * 2 + sh) * N_DIM + nb * 128 + tid] = sc[tid];
}

// ---------------- softmax over n (sums the 2 s-half partials) ----------------
__global__ __launch_bounds__(512) void softmax_kernel(
    const float* __restrict__ partial, float* __restrict__ out)
{
    const int b = blockIdx.x;
    const int n = threadIdx.x;
    const float* p = partial + (size_t)b * 2 * N_DIM;
    float s = p[n] + p[N_DIM + n];

    float m = s;
    #pragma unroll
    for (int off = 1; off < 64; off <<= 1)
        m = fmaxf(m, __shfl_xor(m, off));
    __shared__ float red[8];
    const int wv = n >> 6;
    if ((n & 63) == 0) red[wv] = m;
    __syncthreads();
    float bm = red[0];
    #pragma unroll
    for (int i = 1; i < 8; ++i) bm = fmaxf(bm, red[i]);

    float e = expf(s - bm);
    float t = e;
    #pragma unroll
    for (int off = 1; off < 64; off <<= 1)
        t += __shfl_xor(t, off);
    __syncthreads();
    if ((n & 63) == 0) red[wv] = t;
    __syncthreads();
    float tot = 0.f;
    #pragma unroll
    for (int i = 0; i < 8; ++i) tot += red[i];

    out[(size_t)b * N_DIM + n] = e / tot;
}

extern "C" void kernel_launch(void* const* d_in, const int* in_sizes, int n_in,
                              void* d_out, int out_size, void* d_ws, size_t ws_size,
                              hipStream_t stream) {
    const float* h_t  = (const float*)d_in[0];
    const float* s_t  = (const float*)d_in[1];
    const float* data = (const float*)d_in[2];
    const float* W_e  = (const float*)d_in[3];
    const float* U_e  = (const float*)d_in[4];
    const float* v_e  = (const float*)d_in[5];
    float* out = (float*)d_out;

    const size_t wq_elems      = (size_t)B_DIM * T_DIM;         // f32
    const size_t partial_elems = (size_t)B_DIM * 2 * N_DIM;     // f32
    const size_t u_elems       = (size_t)T_DIM * T_DIM;         // bf16

    float* wq      = (float*)d_ws;
    float* partial = wq + wq_elems;
    __bf16* Uh     = (__bf16*)(partial + partial_elems);

    wq_kernel<<<B_DIM, 256, 0, stream>>>(h_t, s_t, W_e, wq);
    uconv_kernel<<<(int)(u_elems / 512), 256, 0, stream>>>(U_e, Uh);
    fused4_kernel<<<B_DIM * 8, 256, 0, stream>>>(data, Uh, v_e, wq, partial);
    softmax_kernel<<<B_DIM, 512, 0, stream>>>(partial, out);
}